// Round 5
// baseline (30.228 us; speedup 1.0000x reference)
//
#include <hip/hip_runtime.h>

// NcutLoss: N=4, K=8, C=3, H=W=1024, S=1000, R=5, P=81 disk points.
// loss = N*K - sum_{n,k} num[n,k]/den[n,k]
//   num[n,k] = sum_{s,p} wgt[n,s,p]*q[n,k,s,p]*pc[n,k,s]
//   den[n,k] = sum_s pc[n,k,s] * sum_p wgt[n,s,p]
//   wgt = exp(-d2/SIGMA_I^2 - (di^2+dj^2)/SIGMA_X^2), d2 = sum_c (img_n-img_c)^2
//
// R4 change: fully INDEPENDENT waves — no LDS handoff, no __syncthreads, no
// block coupling. One wave per (s, k-half); lane 0 loads its own 4 center
// preds and issues 8 striped atomics. Tests whether barrier coupling was
// capping per-CU outstanding-miss concurrency. Zero-init via graph memset.

constexpr int P = 81;
constexpr int WW = 1024;
constexpr size_t HW = (size_t)1024 * 1024;
constexpr int NN = 4, KK = 8, CC = 3;
constexpr int NSTRIPE = 64;
constexpr float INV_SI2 = 1.0f / 100.0f;  // 1/SIGMA_I^2
constexpr float INV_SX2 = 1.0f / 16.0f;   // 1/SIGMA_X^2

// Disk offsets, row-major over di=-5..5 (order irrelevant: all sums over p).
__device__ __constant__ signed char c_di[P] = {
    -5,
    -4,-4,-4,-4,-4,-4,-4,
    -3,-3,-3,-3,-3,-3,-3,-3,-3,
    -2,-2,-2,-2,-2,-2,-2,-2,-2,
    -1,-1,-1,-1,-1,-1,-1,-1,-1,
     0, 0, 0, 0, 0, 0, 0, 0, 0, 0, 0,
     1, 1, 1, 1, 1, 1, 1, 1, 1,
     2, 2, 2, 2, 2, 2, 2, 2, 2,
     3, 3, 3, 3, 3, 3, 3, 3, 3,
     4, 4, 4, 4, 4, 4, 4,
     5
};
__device__ __constant__ signed char c_dj[P] = {
     0,
    -3,-2,-1, 0, 1, 2, 3,
    -4,-3,-2,-1, 0, 1, 2, 3, 4,
    -4,-3,-2,-1, 0, 1, 2, 3, 4,
    -4,-3,-2,-1, 0, 1, 2, 3, 4,
    -5,-4,-3,-2,-1, 0, 1, 2, 3, 4, 5,
    -4,-3,-2,-1, 0, 1, 2, 3, 4,
    -4,-3,-2,-1, 0, 1, 2, 3, 4,
    -4,-3,-2,-1, 0, 1, 2, 3, 4,
    -3,-2,-1, 0, 1, 2, 3,
     0
};

__global__ __launch_bounds__(256) void ncut_accum(
    const float* __restrict__ pred,   // (N,K,H,W)
    const float* __restrict__ imgs,   // (N,C,H,W)
    const long long* __restrict__ hs, // (S,)
    const long long* __restrict__ wsm,// (S,)
    float* __restrict__ acc,          // NSTRIPE x 64 floats
    int S)
{
    const int tid   = threadIdx.x;
    const int lane  = tid & 63;
    const int wv    = tid >> 6;       // 0..3
    const int sl    = wv >> 1;        // local sample 0..1
    const int khalf = wv & 1;         // k-half: 0 -> k=0..3, 1 -> k=4..7

    const int n = blockIdx.y;
    const int s = blockIdx.x * 2 + sl;
    if (s >= S) return;               // wave-uniform exit; no barriers anywhere

    const int h = (int)hs[s] + 5;
    const int w = (int)wsm[s] + 5;
    const float* img_n = imgs + (size_t)n * CC * HW;
    const size_t coff = (size_t)h * WW + w;
    const float* pn = pred + (size_t)n * KK * HW;
    const float* pk = pn + (size_t)(khalf * 4) * HW;

    const float c0 = img_n[coff];
    const float c1 = img_n[HW + coff];
    const float c2 = img_n[2 * HW + coff];

    float wsum = 0.0f;
    float qw[4] = {0.f, 0.f, 0.f, 0.f};

    #pragma unroll
    for (int rep = 0; rep < 2; ++rep) {
        const int p = lane + rep * 64;
        if (p < P) {
            const int di = (int)c_di[p];
            const int dj = (int)c_dj[p];
            const size_t off = (size_t)(h + di) * WW + (w + dj);
            const float d0 = img_n[off]          - c0;
            const float d1 = img_n[HW + off]     - c1;
            const float d2 = img_n[2 * HW + off] - c2;
            const float r2 = (float)(di * di + dj * dj);
            const float wgt = __expf(-((d0*d0 + d1*d1 + d2*d2) * INV_SI2
                                       + r2 * INV_SX2));
            wsum += wgt;
            const float* qb = pk + off;
            #pragma unroll
            for (int j = 0; j < 4; ++j)
                qw[j] += wgt * qb[(size_t)j * HW];
        }
    }

    // 64-lane butterfly over 5 values; lane 0 ends with totals.
    #pragma unroll
    for (int off = 32; off; off >>= 1) {
        wsum += __shfl_xor(wsum, off);
        #pragma unroll
        for (int j = 0; j < 4; ++j)
            qw[j] += __shfl_xor(qw[j], off);
    }

    if (lane == 0) {
        float pv[4];
        #pragma unroll
        for (int j = 0; j < 4; ++j)
            pv[j] = pn[(size_t)(khalf * 4 + j) * HW + coff];
        float* st = acc + (size_t)(blockIdx.x & (NSTRIPE - 1)) * 64;
        #pragma unroll
        for (int j = 0; j < 4; ++j) {
            const int k = khalf * 4 + j;
            atomicAdd(&st[n * KK + k],      pv[j] * qw[j]);
            atomicAdd(&st[32 + n * KK + k], pv[j] * wsum);
        }
    }
}

__global__ void ncut_final(const float* __restrict__ acc, float* __restrict__ out) {
    const int tid = threadIdx.x;  // 64 threads: tid<32 num slots, tid>=32 den slots
    float v = 0.0f;
    #pragma unroll 8
    for (int st = 0; st < NSTRIPE; ++st)
        v += acc[st * 64 + tid];
    const float den = __shfl_xor(v, 32);     // lane t<32 gets matching den
    float r = (tid < 32) ? v / den : 0.0f;
    #pragma unroll
    for (int off = 32; off; off >>= 1)
        r += __shfl_xor(r, off);
    if (tid == 0) out[0] = (float)(NN * KK) - r;
}

extern "C" void kernel_launch(void* const* d_in, const int* in_sizes, int n_in,
                              void* d_out, int out_size, void* d_ws, size_t ws_size,
                              hipStream_t stream) {
    const float* pred     = (const float*)d_in[0];
    const float* imgs     = (const float*)d_in[1];
    const long long* hs   = (const long long*)d_in[2];
    const long long* wsm  = (const long long*)d_in[3];
    const int S = in_sizes[2];
    float* acc = (float*)d_ws;   // NSTRIPE * 64 floats = 16 KB
    float* out = (float*)d_out;

    hipMemsetAsync(acc, 0, NSTRIPE * 64 * sizeof(float), stream);
    dim3 grid((S + 1) / 2, NN);   // 4 independent waves/block: 2 samples x 2 k-halves
    ncut_accum<<<grid, 256, 0, stream>>>(pred, imgs, hs, wsm, acc, S);
    ncut_final<<<1, 64, 0, stream>>>(acc, out);
}

// Round 6
// 26.221 us; speedup vs baseline: 1.1528x; 1.1528x over previous
//
#include <hip/hip_runtime.h>

// NcutLoss: N=4, K=8, C=3, H=W=1024, S=1000, R=5, P=81 disk points.
// loss = N*K - sum_{n,k} num[n,k]/den[n,k]
//   num[n,k] = sum_{s,p} wgt*q*pc ; den[n,k] = sum_s pc*sum_p wgt
//   wgt = exp(-d2/SIGMA_I^2 - (di^2+dj^2)/SIGMA_X^2)
//
// R5: two waves per (n,s) split by DISK ROW (rows -5..-1: 35 pts / rows 0..5:
// 46 pts) -> disjoint cache lines, zero redundant gather, single rep, 8000
// waves (~31/CU). pv prefetched on lanes 0-7 before gather; 16-lane parallel
// striped atomics. No LDS, no barriers.

constexpr int P = 81;
constexpr int WW = 1024;
constexpr size_t HW = (size_t)1024 * 1024;
constexpr int NN = 4, KK = 8, CC = 3;
constexpr int NSTRIPE = 64;
constexpr float INV_SI2 = 1.0f / 100.0f;  // 1/SIGMA_I^2
constexpr float INV_SX2 = 1.0f / 16.0f;   // 1/SIGMA_X^2

// Disk offsets, row-major over di=-5..5. Row boundaries: p 0..34 rows -5..-1,
// p 35..80 rows 0..+5.
__device__ __constant__ signed char c_di[P] = {
    -5,
    -4,-4,-4,-4,-4,-4,-4,
    -3,-3,-3,-3,-3,-3,-3,-3,-3,
    -2,-2,-2,-2,-2,-2,-2,-2,-2,
    -1,-1,-1,-1,-1,-1,-1,-1,-1,
     0, 0, 0, 0, 0, 0, 0, 0, 0, 0, 0,
     1, 1, 1, 1, 1, 1, 1, 1, 1,
     2, 2, 2, 2, 2, 2, 2, 2, 2,
     3, 3, 3, 3, 3, 3, 3, 3, 3,
     4, 4, 4, 4, 4, 4, 4,
     5
};
__device__ __constant__ signed char c_dj[P] = {
     0,
    -3,-2,-1, 0, 1, 2, 3,
    -4,-3,-2,-1, 0, 1, 2, 3, 4,
    -4,-3,-2,-1, 0, 1, 2, 3, 4,
    -4,-3,-2,-1, 0, 1, 2, 3, 4,
    -5,-4,-3,-2,-1, 0, 1, 2, 3, 4, 5,
    -4,-3,-2,-1, 0, 1, 2, 3, 4,
    -4,-3,-2,-1, 0, 1, 2, 3, 4,
    -4,-3,-2,-1, 0, 1, 2, 3, 4,
    -3,-2,-1, 0, 1, 2, 3,
     0
};

__global__ __launch_bounds__(256) void ncut_accum(
    const float* __restrict__ pred,   // (N,K,H,W)
    const float* __restrict__ imgs,   // (N,C,H,W)
    const long long* __restrict__ hs, // (S,)
    const long long* __restrict__ wsm,// (S,)
    float* __restrict__ acc,          // NSTRIPE x 64 floats
    int S)
{
    const int tid  = threadIdx.x;
    const int lane = tid & 63;
    const int wv   = tid >> 6;        // 0..3
    const int sl   = wv >> 1;         // local sample 0..1
    const int half = wv & 1;          // 0: disk rows -5..-1, 1: rows 0..+5

    const int n = blockIdx.y;
    const int s = blockIdx.x * 2 + sl;
    if (s >= S) return;               // wave-uniform; no barriers anywhere

    const int h = (int)hs[s] + 5;
    const int w = (int)wsm[s] + 5;
    const float* img_n = imgs + (size_t)n * CC * HW;
    const size_t coff = (size_t)h * WW + w;
    const float* pn = pred + (size_t)n * KK * HW;

    // Prefetch center preds on lanes 0..7 (latency hidden under the gather).
    float pv = 0.0f;
    if (lane < KK) pv = pn[(size_t)lane * HW + coff];

    const float c0 = img_n[coff];
    const float c1 = img_n[HW + coff];
    const float c2 = img_n[2 * HW + coff];

    // This wave's disk-row half: disjoint rows -> disjoint cache lines.
    const int base = half ? 35 : 0;
    const int npts = half ? 46 : 35;

    float wsum = 0.0f;
    float qw[KK] = {0.f,0.f,0.f,0.f,0.f,0.f,0.f,0.f};

    if (lane < npts) {
        const int p  = base + lane;
        const int di = (int)c_di[p];
        const int dj = (int)c_dj[p];
        const size_t off = (size_t)(h + di) * WW + (w + dj);
        const float d0 = img_n[off]          - c0;
        const float d1 = img_n[HW + off]     - c1;
        const float d2 = img_n[2 * HW + off] - c2;
        const float r2 = (float)(di * di + dj * dj);
        const float wgt = __expf(-((d0*d0 + d1*d1 + d2*d2) * INV_SI2
                                   + r2 * INV_SX2));
        wsum = wgt;
        const float* qb = pn + off;
        #pragma unroll
        for (int k = 0; k < KK; ++k)
            qw[k] = wgt * qb[(size_t)k * HW];
    }

    // 64-lane butterfly over 9 values; all lanes end with this wave's totals.
    #pragma unroll
    for (int off = 32; off; off >>= 1) {
        wsum += __shfl_xor(wsum, off);
        #pragma unroll
        for (int k = 0; k < KK; ++k)
            qw[k] += __shfl_xor(qw[k], off);
    }

    // 16-lane parallel epilogue: lanes 0..7 -> num[k], lanes 8..15 -> den[k].
    if (lane < 16) {
        const int k = lane & 7;
        const float pvv = __shfl(pv, k);   // pv[k] from lane k
        float q = qw[0];
        #pragma unroll
        for (int j = 1; j < KK; ++j)
            if (k == j) q = qw[j];
        const float val = (lane < 8) ? pvv * q : pvv * wsum;
        float* st = acc + (size_t)(blockIdx.x & (NSTRIPE - 1)) * 64;
        atomicAdd(&st[(lane < 8 ? 0 : 32) + n * KK + k], val);
    }
}

__global__ void ncut_final(const float* __restrict__ acc, float* __restrict__ out) {
    const int tid = threadIdx.x;  // 64 threads: tid<32 num slots, tid>=32 den slots
    float v = 0.0f;
    #pragma unroll 8
    for (int st = 0; st < NSTRIPE; ++st)
        v += acc[st * 64 + tid];
    const float den = __shfl_xor(v, 32);     // lane t<32 gets matching den
    float r = (tid < 32) ? v / den : 0.0f;
    #pragma unroll
    for (int off = 32; off; off >>= 1)
        r += __shfl_xor(r, off);
    if (tid == 0) out[0] = (float)(NN * KK) - r;
}

extern "C" void kernel_launch(void* const* d_in, const int* in_sizes, int n_in,
                              void* d_out, int out_size, void* d_ws, size_t ws_size,
                              hipStream_t stream) {
    const float* pred     = (const float*)d_in[0];
    const float* imgs     = (const float*)d_in[1];
    const long long* hs   = (const long long*)d_in[2];
    const long long* wsm  = (const long long*)d_in[3];
    const int S = in_sizes[2];
    float* acc = (float*)d_ws;   // NSTRIPE * 64 floats = 16 KB
    float* out = (float*)d_out;

    hipMemsetAsync(acc, 0, NSTRIPE * 64 * sizeof(float), stream);
    dim3 grid((S + 1) / 2, NN);   // 4 waves/block: 2 samples x 2 disk-row halves
    ncut_accum<<<grid, 256, 0, stream>>>(pred, imgs, hs, wsm, acc, S);
    ncut_final<<<1, 64, 0, stream>>>(acc, out);
}